// Round 2
// baseline (144.567 us; speedup 1.0000x reference)
//
#include <hip/hip_runtime.h>

#define S 128
#define BAND 8                        // rows per halfwave band
#define BANDS_PER_PLANE (S / BAND)    // 16
#define NPLANES 1024                  // B*C
#define NBLOCKS (NPLANES * BANDS_PER_PLANE / 8)   // 2048 blocks, 8 halfwaves each

struct Win { float m[6]; };   // [left | v.x v.y v.z v.w | right]

__device__ __forceinline__ Win load_win(const float* __restrict__ xp, int rr,
                                        int colbase) {
    Win w;
    if (rr >= 0 && rr < S) {
        const float* row = xp + rr * S + colbase;
        const float4 v = *reinterpret_cast<const float4*>(row);
        const float l = (colbase > 0)     ? row[-1] : 0.f;   // left zero-pad at w=0
        const float r = (colbase + 4 < S) ? row[4]  : 0.f;   // right zero-pad at w=127
        w.m[0] = l; w.m[1] = v.x; w.m[2] = v.y; w.m[3] = v.z; w.m[4] = v.w; w.m[5] = r;
    } else {
        #pragma unroll
        for (int i = 0; i < 6; ++i) w.m[i] = 0.f;            // top/bottom zero-pad rows
    }
    return w;
}

__global__ __launch_bounds__(256, 8) void pairwise_potential_kernel(
    const float* __restrict__ x, const float* __restrict__ w1,
    const float* __restrict__ w2, float* __restrict__ out)
{
    const int tid    = threadIdx.x;
    const int hw     = tid >> 5;      // halfwave index in block (0..7)
    const int lane32 = tid & 31;

    const int g     = blockIdx.x * 8 + hw;       // global band id
    const int plane = g >> 4;                    // b*64 + c   (16 bands/plane)
    const int band  = g & 15;
    const int r0    = band * BAND;
    const int c     = plane & 63;

    const float* xp  = x   + (size_t)plane * (S * S);
    const float* w1p = w1  + (size_t)c     * (S * S);
    const float* w2p = w2  + (size_t)c     * (S * S);
    float*       op  = out + (size_t)plane * (S * S);
    const int colbase = lane32 * 4;

    // constants (1/9 folded into the exp weights)
    const float NL  = -0.72134752044f;    // -0.5 * log2(e)
    const float E1N = 0.06739229552f;     // exp(-0.5)/9        (d = 1)
    const float E2N = 0.05478541015f;     // exp(-sqrt2/2)/9    (d = sqrt2)
    const float C9  = 0.11111111111f;     // exp(0)/9           (dx=dy=0 term)
    const float W2C = 1.07298380550f;     // (4 + 4*sqrt(2)) / 9

    Win R0 = load_win(xp, r0 - 1, colbase);
    Win R1 = load_win(xp, r0,     colbase);

    for (int h = r0; h < r0 + BAND; ++h) {
        Win R2 = load_win(xp, h + 1, colbase);
        const float4 w1v = *reinterpret_cast<const float4*>(w1p + h * S + colbase);
        const float4 w2v = *reinterpret_cast<const float4*>(w2p + h * S + colbase);
        const float* w1a = &w1v.x;
        const float* w2a = &w2v.x;

        float4 o;
        float* ov = &o.x;
        #pragma unroll
        for (int k = 0; k < 4; ++k) {
            const float cen = R0.m[k];            // X(h-1, w-1): window root
            float d;
            // d = 1 group (offsets (0,1),(0,2),(1,0),(2,0) from the root)
            d = cen - R0.m[k + 1]; const float a0 = __builtin_amdgcn_exp2f(d * d * NL);
            d = cen - R0.m[k + 2]; const float a1 = __builtin_amdgcn_exp2f(d * d * NL);
            d = cen - R1.m[k];     const float a2 = __builtin_amdgcn_exp2f(d * d * NL);
            d = cen - R2.m[k];     const float a3 = __builtin_amdgcn_exp2f(d * d * NL);
            // d = sqrt2 group (offsets (1,1),(1,2),(2,1),(2,2))
            d = cen - R1.m[k + 1]; const float b0 = __builtin_amdgcn_exp2f(d * d * NL);
            d = cen - R1.m[k + 2]; const float b1 = __builtin_amdgcn_exp2f(d * d * NL);
            d = cen - R2.m[k + 1]; const float b2 = __builtin_amdgcn_exp2f(d * d * NL);
            d = cen - R2.m[k + 2]; const float b3 = __builtin_amdgcn_exp2f(d * d * NL);
            const float s1 = (a0 + a1) + (a2 + a3);
            const float s2 = (b0 + b1) + (b2 + b3);
            const float fN = fmaf(E2N, s2, fmaf(E1N, s1, C9));   // first/9
            ov[k] = fmaf(w1a[k], fN, w2a[k] * W2C);
        }
        *reinterpret_cast<float4*>(op + h * S + colbase) = o;
        R0 = R1; R1 = R2;
    }
}

extern "C" void kernel_launch(void* const* d_in, const int* in_sizes, int n_in,
                              void* d_out, int out_size, void* d_ws, size_t ws_size,
                              hipStream_t stream) {
    const float* x  = (const float*)d_in[0];
    const float* w1 = (const float*)d_in[1];
    const float* w2 = (const float*)d_in[2];
    float* out = (float*)d_out;
    pairwise_potential_kernel<<<NBLOCKS, 256, 0, stream>>>(x, w1, w2, out);
}

// Round 3
// 133.704 us; speedup vs baseline: 1.0813x; 1.0813x over previous
//
#include <hip/hip_runtime.h>

#define S 128
#define BAND 4
#define BANDS_PER_PLANE (S / BAND)    // 32
#define NPLANES 1024                  // B*C
#define NBLOCKS (NPLANES * BANDS_PER_PLANE / 8)   // 4096 blocks, 8 halfwave-bands each

__global__ __launch_bounds__(256, 4) void pairwise_potential_kernel(
    const float* __restrict__ x, const float* __restrict__ w1,
    const float* __restrict__ w2, float* __restrict__ out)
{
    const int tid    = threadIdx.x;
    const int hw     = tid >> 5;      // halfwave index (0..7)
    const int lane32 = tid & 31;

    const int g     = blockIdx.x * 8 + hw;       // global band id
    const int plane = g >> 5;                    // 32 bands/plane
    const int band  = g & 31;
    const int r0    = band * BAND;
    const int c     = plane & 63;

    const float* xp  = x   + (size_t)plane * (S * S);
    const float* w1p = w1  + (size_t)c     * (S * S);
    const float* w2p = w2  + (size_t)c     * (S * S);
    float*       op  = out + (size_t)plane * (S * S);
    const int colbase = lane32 * 4;

    const float NL  = -0.72134752044f;    // -0.5 * log2(e)
    const float E1N = 0.06739229552f;     // exp(-0.5)/9        (d = 1)
    const float E2N = 0.05478541015f;     // exp(-sqrt2/2)/9    (d = sqrt2)
    const float C9  = 0.11111111111f;     // exp(0)/9           (center term)
    const float W2C = 1.07298380550f;     // (4 + 4*sqrt(2)) / 9

    // ---- batched, branchless loads: 6 window rows + halos ----
    float4 xv[BAND + 2];
    float  xl[BAND + 2], xh[BAND + 2];
    #pragma unroll
    for (int i = 0; i < BAND + 2; ++i) {
        const int rr = r0 - 1 + i;
        const int rc = min(max(rr, 0), S - 1);        // clamp; masked below
        const float* row = xp + rc * S + colbase;
        xv[i] = *reinterpret_cast<const float4*>(row);
        const float lv = row[(lane32 == 0)  ? 0 : -1];  // clamped halo addr
        const float rv = row[(lane32 == 31) ? 3 :  4];
        xl[i] = (lane32 == 0)  ? 0.f : lv;
        xh[i] = (lane32 == 31) ? 0.f : rv;
    }
    // vertical zero-pad: only first/last window rows can be out of range
    {
        const float mt = (band == 0) ? 0.f : 1.f;
        xv[0].x *= mt; xv[0].y *= mt; xv[0].z *= mt; xv[0].w *= mt;
        xl[0] *= mt; xh[0] *= mt;
        const float mb = (band == BANDS_PER_PLANE - 1) ? 0.f : 1.f;
        xv[BAND+1].x *= mb; xv[BAND+1].y *= mb; xv[BAND+1].z *= mb; xv[BAND+1].w *= mb;
        xl[BAND+1] *= mb; xh[BAND+1] *= mb;
    }

    // ---- batched w loads for the whole band ----
    float4 w1v[BAND], w2v[BAND];
    #pragma unroll
    for (int r = 0; r < BAND; ++r) {
        w1v[r] = *reinterpret_cast<const float4*>(w1p + (r0 + r) * S + colbase);
        w2v[r] = *reinterpret_cast<const float4*>(w2p + (r0 + r) * S + colbase);
    }

    // ---- compute ----
    #pragma unroll
    for (int r = 0; r < BAND; ++r) {
        float m0[6], m1[6], m2[6];
        m0[0] = xl[r];     m0[1] = xv[r].x;     m0[2] = xv[r].y;     m0[3] = xv[r].z;     m0[4] = xv[r].w;     m0[5] = xh[r];
        m1[0] = xl[r + 1]; m1[1] = xv[r + 1].x; m1[2] = xv[r + 1].y; m1[3] = xv[r + 1].z; m1[4] = xv[r + 1].w; m1[5] = xh[r + 1];
        m2[0] = xl[r + 2]; m2[1] = xv[r + 2].x; m2[2] = xv[r + 2].y; m2[3] = xv[r + 2].z; m2[4] = xv[r + 2].w; m2[5] = xh[r + 2];

        const float* w1a = &w1v[r].x;
        const float* w2a = &w2v[r].x;
        float4 o;
        float* ov = &o.x;
        #pragma unroll
        for (int k = 0; k < 4; ++k) {
            const float cen = m0[k];             // X(h-1, w-1): window root
            float d;
            d = cen - m0[k + 1]; const float a0 = __builtin_amdgcn_exp2f(d * d * NL);
            d = cen - m0[k + 2]; const float a1 = __builtin_amdgcn_exp2f(d * d * NL);
            d = cen - m1[k];     const float a2 = __builtin_amdgcn_exp2f(d * d * NL);
            d = cen - m2[k];     const float a3 = __builtin_amdgcn_exp2f(d * d * NL);
            d = cen - m1[k + 1]; const float b0 = __builtin_amdgcn_exp2f(d * d * NL);
            d = cen - m1[k + 2]; const float b1 = __builtin_amdgcn_exp2f(d * d * NL);
            d = cen - m2[k + 1]; const float b2 = __builtin_amdgcn_exp2f(d * d * NL);
            d = cen - m2[k + 2]; const float b3 = __builtin_amdgcn_exp2f(d * d * NL);
            const float s1 = (a0 + a1) + (a2 + a3);
            const float s2 = (b0 + b1) + (b2 + b3);
            const float fN = fmaf(E2N, s2, fmaf(E1N, s1, C9));   // first/9
            ov[k] = fmaf(w1a[k], fN, w2a[k] * W2C);
        }
        *reinterpret_cast<float4*>(op + (r0 + r) * S + colbase) = o;
    }
}

extern "C" void kernel_launch(void* const* d_in, const int* in_sizes, int n_in,
                              void* d_out, int out_size, void* d_ws, size_t ws_size,
                              hipStream_t stream) {
    const float* x  = (const float*)d_in[0];
    const float* w1 = (const float*)d_in[1];
    const float* w2 = (const float*)d_in[2];
    float* out = (float*)d_out;
    pairwise_potential_kernel<<<NBLOCKS, 256, 0, stream>>>(x, w1, w2, out);
}